// Round 25
// baseline (60.416 us; speedup 1.0000x reference)
//
#include <hip/hip_runtime.h>
#include <hip/hip_bf16.h>
#include <math.h>

#define S_LEN 1024
#define BATCH 32
#define EMB   128
#define NHEAD 4
#define HDIM  32
#define BHN   (BATCH*NHEAD)          // 128
#define HBUF  (BHN*S_LEN*HDIM)       // 4194304 elements per q/k/v (bf16)
#define NTOK  (S_LEN*BATCH)          // 32768

typedef __attribute__((ext_vector_type(4))) float f32x4;
typedef __attribute__((ext_vector_type(8))) short bf16x8;
typedef __attribute__((ext_vector_type(4))) short bf16x4;
typedef __attribute__((ext_vector_type(2))) unsigned int u32x2;
typedef __attribute__((ext_vector_type(4))) unsigned int u32x4;

// (1/sqrt(32)) * log2(e): folded into Wq/bq by wcvt_kernel
#define Q_PRESCALE 0.25503588f

__device__ __forceinline__ unsigned short f2bf(float f) {
    union { float f; unsigned u; } v; v.f = f;
    unsigned r = v.u + 0x7fff + ((v.u >> 16) & 1);   // RNE
    return (unsigned short)(r >> 16);
}

__device__ __forceinline__ void gl_lds16(const void* g, void* l) {
    __builtin_amdgcn_global_load_lds(
        (const __attribute__((address_space(1))) unsigned*)g,
        (__attribute__((address_space(3))) unsigned*)l, 16, 0, 0);
}

// ---------------- Kernel 0: weight/bias convert (fp32 -> bf16) -------------
__global__ __launch_bounds__(256)
void wcvt_kernel(const float* __restrict__ w, const float* __restrict__ bias,
                 const float* __restrict__ wo, const float* __restrict__ bo,
                 __hip_bfloat16* __restrict__ wbf,
                 __hip_bfloat16* __restrict__ wobf,
                 float* __restrict__ biasf)
{
    const int bid = blockIdx.x, tid = threadIdx.x;
    if (bid < 48) {
        int e = bid * 1024 + tid * 4;
        float4 v = *(const float4*)(w + e);
        float s = (e < 128 * 128) ? Q_PRESCALE : 1.f;
        bf16x4 o;
        o[0] = (short)f2bf(v.x * s); o[1] = (short)f2bf(v.y * s);
        o[2] = (short)f2bf(v.z * s); o[3] = (short)f2bf(v.w * s);
        *(bf16x4*)(wbf + e) = o;
    } else if (bid < 64) {
        int e = (bid - 48) * 1024 + tid * 4;
        float4 v = *(const float4*)(wo + e);
        bf16x4 o;
        o[0] = (short)f2bf(v.x); o[1] = (short)f2bf(v.y);
        o[2] = (short)f2bf(v.z); o[3] = (short)f2bf(v.w);
        *(bf16x4*)(wobf + e) = o;
    } else if (tid < 96) {
        int e = tid * 4;
        float4 v = *(const float4*)(bias + e);
        float s = (e < 128) ? Q_PRESCALE : 1.f;
        v.x *= s; v.y *= s; v.z *= s; v.w *= s;
        *(float4*)(biasf + e) = v;
    } else if (tid < 128) {
        int e = (tid - 96) * 4;
        *(float4*)(biasf + 384 + e) = *(const float4*)(bo + e);
    }
}

// ---------------- Kernel 1: QKV projection, bf16 MFMA ----------------
__global__ __launch_bounds__(256)
void qkv_mfma_kernel(const float* __restrict__ x,
                     const __hip_bfloat16* __restrict__ wbf,
                     const float* __restrict__ biasf,
                     __hip_bfloat16* __restrict__ qb,
                     __hip_bfloat16* __restrict__ kb,
                     __hip_bfloat16* __restrict__ vtb)
{
    __shared__ __align__(16) unsigned char smem[17408 + 32768];
    __hip_bfloat16* xs = (__hip_bfloat16*)smem;            // [64][136] padded
    __hip_bfloat16* wl = (__hip_bfloat16*)(smem + 17408);  // [128][128] XOR-swz
    const int tid   = threadIdx.x;
    const int mt    = blockIdx.x;
    const int which = blockIdx.y;        // 0=q 1=k 2=v
    const int b0 = (mt & 7) * 4;
    const int s0 = (mt >> 3) * 16;

    const __hip_bfloat16* wsec = wbf + which * (128 * 128);
    #pragma unroll
    for (int j = 0; j < 8; ++j) {
        int idx = tid + j * 256;
        int fl = idx >> 4, c = idx & 15;
        int cs = c ^ (fl & 15);
        gl_lds16(wsec + fl * 128 + cs * 8, wl + idx * 8);
    }
    #pragma unroll
    for (int j = 0; j < 8; ++j) {
        int idx = tid + j * 256;
        int lt = idx >> 5, c4 = idx & 31;
        int t = (s0 + (lt & 15)) * 32 + b0 + (lt >> 4);
        float4 v = *(const float4*)(x + (size_t)t * 128 + c4 * 4);
        bf16x4 o;
        o[0] = (short)f2bf(v.x); o[1] = (short)f2bf(v.y);
        o[2] = (short)f2bf(v.z); o[3] = (short)f2bf(v.w);
        *(bf16x4*)(xs + lt * 136 + c4 * 4) = o;
    }
    __syncthreads();

    const int wv = tid >> 6, wm = wv >> 1, wn = wv & 1;
    const int l = tid & 63, q15 = l & 15, g = l >> 4;

    bf16x8 xf[2][4];
    #pragma unroll
    for (int tt = 0; tt < 2; ++tt)
        #pragma unroll
        for (int kc = 0; kc < 4; ++kc)
            xf[tt][kc] = *(const bf16x8*)(xs + (wm * 32 + tt * 16 + q15) * 136
                                          + kc * 32 + 8 * g);

    f32x4 acc[4][2];
    #pragma unroll
    for (int nt = 0; nt < 4; ++nt)
        #pragma unroll
        for (int tt = 0; tt < 2; ++tt)
            acc[nt][tt] = (f32x4){0.f, 0.f, 0.f, 0.f};

    #pragma unroll
    for (int nt = 0; nt < 4; ++nt) {
        const int fl = wn * 64 + nt * 16 + q15;
        #pragma unroll
        for (int kc = 0; kc < 4; ++kc) {
            bf16x8 wf = *(const bf16x8*)(wl + fl * 128
                                         + (((kc * 4 + g) ^ q15) * 8));
            acc[nt][0] = __builtin_amdgcn_mfma_f32_16x16x32_bf16(wf, xf[0][kc], acc[nt][0], 0, 0, 0);
            acc[nt][1] = __builtin_amdgcn_mfma_f32_16x16x32_bf16(wf, xf[1][kc], acc[nt][1], 0, 0, 0);
        }
    }
    __syncthreads();
    __hip_bfloat16* ol = wl;

    if (which < 2) {
        #pragma unroll
        for (int nt = 0; nt < 4; ++nt) {
            float4 bv = *(const float4*)(biasf + which * 128 + wn * 64 + nt * 16 + 4 * g);
            #pragma unroll
            for (int tt = 0; tt < 2; ++tt) {
                bf16x4 pk;
                pk[0] = (short)f2bf(acc[nt][tt][0] + bv.x);
                pk[1] = (short)f2bf(acc[nt][tt][1] + bv.y);
                pk[2] = (short)f2bf(acc[nt][tt][2] + bv.z);
                pk[3] = (short)f2bf(acc[nt][tt][3] + bv.w);
                *(bf16x4*)(ol + (wm * 32 + tt * 16 + q15) * 136
                           + wn * 64 + nt * 16 + 4 * g) = pk;
            }
        }
        __syncthreads();
        const int bb = tid >> 6, rr = tid & 63, ss = rr >> 2, c4 = rr & 3;
        __hip_bfloat16* dst = (which == 0) ? qb : kb;
        #pragma unroll
        for (int i = 0; i < 4; ++i) {
            bf16x8 vv = *(const bf16x8*)(ol + (bb * 16 + ss) * 136 + i * 32 + c4 * 8);
            *(bf16x8*)(dst + ((size_t)((b0 + bb) * 4 + i)) * 32768
                       + (s0 + ss) * 32 + c4 * 8) = vv;
        }
    } else {
        #pragma unroll
        for (int nt = 0; nt < 4; ++nt) {
            float4 bv = *(const float4*)(biasf + 256 + wn * 64 + nt * 16 + 4 * g);
            const float* bvp = (const float*)&bv;
            #pragma unroll
            for (int tt = 0; tt < 2; ++tt) {
                #pragma unroll
                for (int r = 0; r < 4; ++r) {
                    int f = wn * 64 + nt * 16 + 4 * g + r;
                    ol[f * 72 + wm * 32 + tt * 16 + q15] =
                        __float2bfloat16(acc[nt][tt][r] + bvp[r]);
                }
            }
        }
        __syncthreads();
        const int bb = tid >> 6, rr = tid & 63, fln = rr >> 1, sh = rr & 1;
        #pragma unroll
        for (int i = 0; i < 4; ++i) {
            int f = i * 32 + fln;
            bf16x8 vv = *(const bf16x8*)(ol + f * 72 + bb * 16 + sh * 8);
            *(bf16x8*)(vtb + ((size_t)((b0 + bb) * 4 + i)) * 32768
                       + (size_t)fln * 1024 + s0 + sh * 8) = vv;
        }
    }
}

// ---------------- Kernel 2: flash attention, counted-vmcnt pipeline ---------
// grid (BH=128, 8), block 256 (4 waves x 32 queries). K/V TRIPLE-buffered in
// LDS: stage tile t+2 while computing t; raw s_barrier with counted
// s_waitcnt vmcnt(2) -- no full vmcnt(0) drain in the steady loop.
// Register-P PV (sigma_g key order), shared K/V fragments across the 2 query
// sub-tiles, no softmax max, ones-B-operand MFMA row sums.
__global__ __launch_bounds__(256)
void attn_kernel(const __hip_bfloat16* __restrict__ qg,
                 const __hip_bfloat16* __restrict__ kg,
                 const __hip_bfloat16* __restrict__ vtg,
                 __hip_bfloat16* __restrict__ att)
{
    __shared__ __hip_bfloat16 Kl[3][64 * 32];
    __shared__ __hip_bfloat16 Vl[3][32 * 64];

    const int tid = threadIdx.x;
    const int w   = tid >> 6;
    const int l   = tid & 63;
    const int q15 = l & 15;
    const int g   = l >> 4;
    const int bh  = blockIdx.x;
    const int qt  = blockIdx.y;          // 0..7, 128 queries per block

    const __hip_bfloat16* kp  = kg  + (size_t)bh * (S_LEN * HDIM);
    const __hip_bfloat16* vtp = vtg + (size_t)bh * (HDIM * S_LEN);

    const int qrow = qt * 128 + w * 32 + q15;
    const __hip_bfloat16* qbase = qg + (size_t)bh * (S_LEN * HDIM);
    bf16x8 qf0 = *(const bf16x8*)(qbase + (size_t)qrow * HDIM + 8 * g);
    bf16x8 qf1 = *(const bf16x8*)(qbase + (size_t)(qrow + 16) * HDIM + 8 * g);

    f32x4 acc00 = {0.f,0.f,0.f,0.f}, acc01 = {0.f,0.f,0.f,0.f}, accs0 = {0.f,0.f,0.f,0.f};
    f32x4 acc10 = {0.f,0.f,0.f,0.f}, acc11 = {0.f,0.f,0.f,0.f}, accs1 = {0.f,0.f,0.f,0.f};

    const short ONE = (short)0x3F80;
    const bf16x8 onef = {ONE, ONE, ONE, ONE, ONE, ONE, ONE, ONE};

    const int kkey = tid >> 2, kd0 = (tid & 3) * 8;
    // V staging: LDS 16B-granule c of row vd holds global granule c^(vd&7)
    const int vd = tid >> 3;
    const int vg0 = ((tid & 7) ^ (vd & 7)) * 8;

    // V read addressing (per lane): rows d0=q15, d1=16+q15 (same &7), byte
    // offset within 16B granule = (g&1)*8; global granule Ga=kc*4+(g>>1),
    // Gb=Ga+2; LDS granule = G ^ (row&7).
    const int vxor = q15 & 7;
    const int vbo  = (g & 1) * 8;
    const int gh   = g >> 1;

#define STAGE(buf, kt_)                                                     \
    gl_lds16(kp + (size_t)((kt_) * 64 + kkey) * HDIM + kd0,                 \
             (void*)(&Kl[buf][0] + tid * 8));                               \
    gl_lds16(vtp + (size_t)vd * S_LEN + (kt_) * 64 + vg0,                   \
             (void*)(&Vl[buf][0] + tid * 8));

#define COMPUTE(buf)                                                        \
    {                                                                       \
        f32x4 sc0[4], sc1[4];                                               \
        _Pragma("unroll")                                                   \
        for (int sub = 0; sub < 4; ++sub) {                                 \
            bf16x8 kf = *(const bf16x8*)(&Kl[buf][(sub * 16 + q15) * HDIM + 8 * g]); \
            f32x4 z = {0.f, 0.f, 0.f, 0.f};                                 \
            sc0[sub] = __builtin_amdgcn_mfma_f32_16x16x32_bf16(kf, qf0, z, 0, 0, 0); \
            sc1[sub] = __builtin_amdgcn_mfma_f32_16x16x32_bf16(kf, qf1, z, 0, 0, 0); \
        }                                                                   \
        const char* vbase = (const char*)&Vl[buf][0];                       \
        bf16x8 vf00, vf01, vf10, vf11;                                      \
        {                                                                   \
            const int Ga0 = gh,     Gb0 = gh + 2;                           \
            const int Ga1 = 4 + gh, Gb1 = 6 + gh;                           \
            bf16x4 a0 = *(const bf16x4*)(vbase + q15 * 128 + ((Ga0 ^ vxor) * 16) + vbo); \
            bf16x4 a1 = *(const bf16x4*)(vbase + q15 * 128 + ((Gb0 ^ vxor) * 16) + vbo); \
            bf16x4 b0 = *(const bf16x4*)(vbase + (16 + q15) * 128 + ((Ga0 ^ vxor) * 16) + vbo); \
            bf16x4 b1 = *(const bf16x4*)(vbase + (16 + q15) * 128 + ((Gb0 ^ vxor) * 16) + vbo); \
            bf16x4 c0 = *(const bf16x4*)(vbase + q15 * 128 + ((Ga1 ^ vxor) * 16) + vbo); \
            bf16x4 c1 = *(const bf16x4*)(vbase + q15 * 128 + ((Gb1 ^ vxor) * 16) + vbo); \
            bf16x4 d0 = *(const bf16x4*)(vbase + (16 + q15) * 128 + ((Ga1 ^ vxor) * 16) + vbo); \
            bf16x4 d1 = *(const bf16x4*)(vbase + (16 + q15) * 128 + ((Gb1 ^ vxor) * 16) + vbo); \
            vf00 = __builtin_shufflevector(a0, a1, 0, 1, 2, 3, 4, 5, 6, 7); \
            vf01 = __builtin_shufflevector(b0, b1, 0, 1, 2, 3, 4, 5, 6, 7); \
            vf10 = __builtin_shufflevector(c0, c1, 0, 1, 2, 3, 4, 5, 6, 7); \
            vf11 = __builtin_shufflevector(d0, d1, 0, 1, 2, 3, 4, 5, 6, 7); \
        }                                                                   \
        bf16x8 pf00, pf01, pf10, pf11;                                      \
        {                                                                   \
            u32x4 t;                                                        \
            float e0, e1, e2, e3, e4, e5, e6, e7;                           \
            PACKP(pf00, sc0[0], sc0[1])                                     \
            PACKP(pf01, sc0[2], sc0[3])                                     \
            PACKP(pf10, sc1[0], sc1[1])                                     \
            PACKP(pf11, sc1[2], sc1[3])                                     \
        }                                                                   \
        acc00 = __builtin_amdgcn_mfma_f32_16x16x32_bf16(pf00, vf00, acc00, 0, 0, 0); \
        acc01 = __builtin_amdgcn_mfma_f32_16x16x32_bf16(pf00, vf01, acc01, 0, 0, 0); \
        accs0 = __builtin_amdgcn_mfma_f32_16x16x32_bf16(pf00, onef, accs0, 0, 0, 0); \
        acc10 = __builtin_amdgcn_mfma_f32_16x16x32_bf16(pf10, vf00, acc10, 0, 0, 0); \
        acc11 = __builtin_amdgcn_mfma_f32_16x16x32_bf16(pf10, vf01, acc11, 0, 0, 0); \
        accs1 = __builtin_amdgcn_mfma_f32_16x16x32_bf16(pf10, onef, accs1, 0, 0, 0); \
        acc00 = __builtin_amdgcn_mfma_f32_16x16x32_bf16(pf01, vf10, acc00, 0, 0, 0); \
        acc01 = __builtin_amdgcn_mfma_f32_16x16x32_bf16(pf01, vf11, acc01, 0, 0, 0); \
        accs0 = __builtin_amdgcn_mfma_f32_16x16x32_bf16(pf01, onef, accs0, 0, 0, 0); \
        acc10 = __builtin_amdgcn_mfma_f32_16x16x32_bf16(pf11, vf10, acc10, 0, 0, 0); \
        acc11 = __builtin_amdgcn_mfma_f32_16x16x32_bf16(pf11, vf11, acc11, 0, 0, 0); \
        accs1 = __builtin_amdgcn_mfma_f32_16x16x32_bf16(pf11, onef, accs1, 0, 0, 0); \
    }

#define PACKP(dst, SA, SB)                                                \
    e0 = __builtin_amdgcn_exp2f(SA[0]);                                   \
    e1 = __builtin_amdgcn_exp2f(SA[1]);                                   \
    e2 = __builtin_amdgcn_exp2f(SA[2]);                                   \
    e3 = __builtin_amdgcn_exp2f(SA[3]);                                   \
    e4 = __builtin_amdgcn_exp2f(SB[0]);                                   \
    e5 = __builtin_amdgcn_exp2f(SB[1]);                                   \
    e6 = __builtin_amdgcn_exp2f(SB[2]);                                   \
    e7 = __builtin_amdgcn_exp2f(SB[3]);                                   \
    t[0] = __builtin_amdgcn_perm(__float_as_uint(e1),                     \
                                 __float_as_uint(e0), 0x07060302u);       \
    t[1] = __builtin_amdgcn_perm(__float_as_uint(e3),                     \
                                 __float_as_uint(e2), 0x07060302u);       \
    t[2] = __builtin_amdgcn_perm(__float_as_uint(e5),                     \
                                 __float_as_uint(e4), 0x07060302u);       \
    t[3] = __builtin_amdgcn_perm(__float_as_uint(e7),                     \
                                 __float_as_uint(e6), 0x07060302u);       \
    __builtin_memcpy(&dst, &t, 16);

    // ---- prologue: stage tiles 0 and 1; wait only for tile 0
    STAGE(0, 0)
    STAGE(1, 1)
    asm volatile("s_waitcnt vmcnt(2)" ::: "memory");
    __builtin_amdgcn_s_barrier();
    asm volatile("" ::: "memory");

    // ---- steady state: stage t+2, compute t, counted-vmcnt barrier
    #pragma unroll
    for (int kt = 0; kt < 14; ++kt) {
        const int cb = kt % 3;
        const int sb = (kt + 2) % 3;
        STAGE(sb, kt + 2)
        COMPUTE(cb)
        asm volatile("s_waitcnt vmcnt(2)" ::: "memory");
        __builtin_amdgcn_s_barrier();
        asm volatile("" ::: "memory");
        __builtin_amdgcn_sched_barrier(0);
    }
    // ---- kt = 14: nothing left to stage; drain for tile 15
    COMPUTE(2)
    asm volatile("s_waitcnt vmcnt(0)" ::: "memory");
    __builtin_amdgcn_s_barrier();
    asm volatile("" ::: "memory");
    // ---- kt = 15
    COMPUTE(0)

#undef STAGE
#undef COMPUTE
#undef PACKP

    // ---- epilogue: normalize by ones row sums (lane-local), write bf16
    const int b = bh >> 2, h = bh & 3;
    #pragma unroll
    for (int r = 0; r < 4; ++r) {
        const float i0 = 1.f / accs0[r];
        const float i1 = 1.f / accs1[r];
        const int s0r = qt * 128 + w * 32 + 4 * g + r;
        __hip_bfloat16* ap0 = att + ((size_t)s0r * BATCH + b) * EMB + h * HDIM;
        __hip_bfloat16* ap1 = att + ((size_t)(s0r + 16) * BATCH + b) * EMB + h * HDIM;
        ap0[q15]      = __float2bfloat16(acc00[r] * i0);
        ap0[16 + q15] = __float2bfloat16(acc01[r] * i0);
        ap1[q15]      = __float2bfloat16(acc10[r] * i1);
        ap1[16 + q15] = __float2bfloat16(acc11[r] * i1);
    }
}

// ---------------- Kernel 3: out_proj + LN, 32 tok/block, BOTH staged --------
// grid 1024, block 256 (4 waves; wm = token half of 32, wn = f half). Wo
// (32KB) AND att tile (8KB) staged via global_load_lds, XOR-swizzled; LDS
// 41.5KB -> 3 blocks/CU (vs r21's grid-limited 2).
__global__ __launch_bounds__(256)
void proj_ln_mfma(const float* __restrict__ x,
                  const __hip_bfloat16* __restrict__ att,
                  const __hip_bfloat16* __restrict__ wobf,
                  const float* __restrict__ biasf,
                  const float* __restrict__ gm, const float* __restrict__ bt,
                  float* __restrict__ out)
{
    __shared__ __align__(16) unsigned char smem[32768 + 8192 + 512];
    __hip_bfloat16* wl = (__hip_bfloat16*)smem;              // [128][128] XOR-swz
    __hip_bfloat16* al = (__hip_bfloat16*)(smem + 32768);    // [32][128] XOR-swz
    float* red = (float*)(smem + 32768 + 8192);              // [2][64]

    const int tid = threadIdx.x;
    const int t0  = blockIdx.x * 32;

    #pragma unroll
    for (int j = 0; j < 8; ++j) {
        int idx = tid + j * 256;
        int fl = idx >> 4, c = idx & 15;
        int cs = c ^ (fl & 15);
        gl_lds16(wobf + fl * 128 + cs * 8, wl + idx * 8);
    }
    #pragma unroll
    for (int j = 0; j < 2; ++j) {
        int idx = tid + j * 256;
        int fl = idx >> 4, c = idx & 15;
        int cs = c ^ (fl & 15);
        gl_lds16(att + (size_t)(t0 + fl) * 128 + cs * 8, al + idx * 8);
    }
    __syncthreads();

    const int wv = tid >> 6, wm = wv >> 1, wn = wv & 1;
    const int l = tid & 63, q15 = l & 15, g = l >> 4;

    const int trow = t0 + wm * 16 + q15;

    bf16x8 af[4];
    #pragma unroll
    for (int kc = 0; kc < 4; ++kc)
        af[kc] = *(const bf16x8*)(al + (wm * 16 + q15) * 128
                                  + (((kc * 4 + g) ^ q15) * 8));

    f32x4 acc[4];
    #pragma unroll
    for (int nt = 0; nt < 4; ++nt)
        acc[nt] = (f32x4){0.f, 0.f, 0.f, 0.f};

    #pragma unroll
    for (int nt = 0; nt < 4; ++nt) {
        const int fl = wn * 64 + nt * 16 + q15;
        #pragma unroll
        for (int kc = 0; kc < 4; ++kc) {
            bf16x8 wf = *(const bf16x8*)(wl + fl * 128
                                         + (((kc * 4 + g) ^ q15) * 8));
            acc[nt] = __builtin_amdgcn_mfma_f32_16x16x32_bf16(wf, af[kc], acc[nt], 0, 0, 0);
        }
    }

    // ---- bias + residual; per-token partial sums (f split across wn waves)
    float vv[4][4];
    float psum = 0.f, psq = 0.f;
    #pragma unroll
    for (int nt = 0; nt < 4; ++nt) {
        const int f0 = wn * 64 + nt * 16 + 4 * g;
        float4 bv = *(const float4*)(biasf + 384 + f0);
        const float* bvp = (const float*)&bv;
        float4 xv = *(const float4*)(x + (size_t)trow * 128 + f0);
        const float* xvp = (const float*)&xv;
        #pragma unroll
        for (int r = 0; r < 4; ++r) {
            float v = acc[nt][r] + bvp[r] + xvp[r];
            vv[nt][r] = v;
            psum += v;
            psq = fmaf(v, v, psq);
        }
    }
    psum += __shfl_xor(psum, 16);
    psum += __shfl_xor(psum, 32);
    psq  += __shfl_xor(psq, 16);
    psq  += __shfl_xor(psq, 32);
    if (l < 16) {
        int idx = (wn * 2 + wm) * 16 + q15;
        red[idx]      = psum;
        red[64 + idx] = psq;
    }
    __syncthreads();

    const int oidx = ((wn ^ 1) * 2 + wm) * 16 + q15;
    const float s  = psum + red[oidx];
    const float sq = psq  + red[64 + oidx];
    const float mean = s * (1.f / 128.f);
    const float var  = sq * (1.f / 128.f) - mean * mean;
    const float rstd = rsqrtf(var + 1e-5f);

    #pragma unroll
    for (int nt = 0; nt < 4; ++nt) {
        const int f0 = wn * 64 + nt * 16 + 4 * g;
        float4 gv  = *(const float4*)(gm + f0);
        float4 btv = *(const float4*)(bt + f0);
        const float* gvp = (const float*)&gv;
        const float* btp = (const float*)&btv;
        float4 o;
        float* op = (float*)&o;
        #pragma unroll
        for (int r = 0; r < 4; ++r)
            op[r] = (vv[nt][r] - mean) * rstd * gvp[r] + btp[r];
        *(float4*)(out + (size_t)trow * 128 + f0) = o;
    }
}

extern "C" void kernel_launch(void* const* d_in, const int* in_sizes, int n_in,
                              void* d_out, int out_size, void* d_ws, size_t ws_size,
                              hipStream_t stream) {
    const float* x     = (const float*)d_in[0];
    const float* wi    = (const float*)d_in[1];
    const float* bi    = (const float*)d_in[2];
    const float* wo    = (const float*)d_in[3];
    const float* bo    = (const float*)d_in[4];
    const float* gamma = (const float*)d_in[5];
    const float* beta  = (const float*)d_in[6];
    float* out = (float*)d_out;

    unsigned char* wsb = (unsigned char*)d_ws;
    __hip_bfloat16* wbf   = (__hip_bfloat16*)wsb;               // 98304 B
    __hip_bfloat16* wobf  = (__hip_bfloat16*)(wsb + 98304);     // 32768 B
    float*          biasf = (float*)(wsb + 131072);             // 2048 B
    __hip_bfloat16* qb    = (__hip_bfloat16*)(wsb + 133120);    // 8 MB each
    __hip_bfloat16* kb    = qb + HBUF;
    __hip_bfloat16* vtb   = kb + HBUF;
    __hip_bfloat16* att   = vtb + HBUF;                          // 8 MB

    wcvt_kernel<<<65, 256, 0, stream>>>(wi, bi, wo, bo, wbf, wobf, biasf);
    qkv_mfma_kernel<<<dim3(512, 3), 256, 0, stream>>>(x, wbf, biasf, qb, kb, vtb);
    attn_kernel<<<dim3(BHN, 8), 256, 0, stream>>>(qb, kb, vtb, att);
    proj_ln_mfma<<<1024, 256, 0, stream>>>(x, att, wobf, biasf, gamma, beta, out);
}

// Round 26
// 59.065 us; speedup vs baseline: 1.0229x; 1.0229x over previous
//
#include <hip/hip_runtime.h>
#include <hip/hip_bf16.h>
#include <math.h>

#define S_LEN 1024
#define BATCH 32
#define EMB   128
#define NHEAD 4
#define HDIM  32
#define BHN   (BATCH*NHEAD)          // 128
#define HBUF  (BHN*S_LEN*HDIM)       // 4194304 elements per q/k/v (bf16)
#define NTOK  (S_LEN*BATCH)          // 32768

typedef __attribute__((ext_vector_type(4))) float f32x4;
typedef __attribute__((ext_vector_type(8))) short bf16x8;
typedef __attribute__((ext_vector_type(4))) short bf16x4;
typedef __attribute__((ext_vector_type(2))) unsigned int u32x2;
typedef __attribute__((ext_vector_type(4))) unsigned int u32x4;

// (1/sqrt(32)) * log2(e): folded into Wq/bq by wcvt_kernel
#define Q_PRESCALE 0.25503588f

__device__ __forceinline__ unsigned short f2bf(float f) {
    union { float f; unsigned u; } v; v.f = f;
    unsigned r = v.u + 0x7fff + ((v.u >> 16) & 1);   // RNE
    return (unsigned short)(r >> 16);
}

__device__ __forceinline__ void gl_lds16(const void* g, void* l) {
    __builtin_amdgcn_global_load_lds(
        (const __attribute__((address_space(1))) unsigned*)g,
        (__attribute__((address_space(3))) unsigned*)l, 16, 0, 0);
}

// ---------------- Kernel 0: weight/bias convert (fp32 -> bf16) -------------
__global__ __launch_bounds__(256)
void wcvt_kernel(const float* __restrict__ w, const float* __restrict__ bias,
                 const float* __restrict__ wo, const float* __restrict__ bo,
                 __hip_bfloat16* __restrict__ wbf,
                 __hip_bfloat16* __restrict__ wobf,
                 float* __restrict__ biasf)
{
    const int bid = blockIdx.x, tid = threadIdx.x;
    if (bid < 48) {
        int e = bid * 1024 + tid * 4;
        float4 v = *(const float4*)(w + e);
        float s = (e < 128 * 128) ? Q_PRESCALE : 1.f;
        bf16x4 o;
        o[0] = (short)f2bf(v.x * s); o[1] = (short)f2bf(v.y * s);
        o[2] = (short)f2bf(v.z * s); o[3] = (short)f2bf(v.w * s);
        *(bf16x4*)(wbf + e) = o;
    } else if (bid < 64) {
        int e = (bid - 48) * 1024 + tid * 4;
        float4 v = *(const float4*)(wo + e);
        bf16x4 o;
        o[0] = (short)f2bf(v.x); o[1] = (short)f2bf(v.y);
        o[2] = (short)f2bf(v.z); o[3] = (short)f2bf(v.w);
        *(bf16x4*)(wobf + e) = o;
    } else if (tid < 96) {
        int e = tid * 4;
        float4 v = *(const float4*)(bias + e);
        float s = (e < 128) ? Q_PRESCALE : 1.f;
        v.x *= s; v.y *= s; v.z *= s; v.w *= s;
        *(float4*)(biasf + e) = v;
    } else if (tid < 128) {
        int e = (tid - 96) * 4;
        *(float4*)(biasf + 384 + e) = *(const float4*)(bo + e);
    }
}

// ---------------- Kernel 1: QKV projection, bf16 MFMA ----------------
__global__ __launch_bounds__(256)
void qkv_mfma_kernel(const float* __restrict__ x,
                     const __hip_bfloat16* __restrict__ wbf,
                     const float* __restrict__ biasf,
                     __hip_bfloat16* __restrict__ qb,
                     __hip_bfloat16* __restrict__ kb,
                     __hip_bfloat16* __restrict__ vtb)
{
    __shared__ __align__(16) unsigned char smem[17408 + 32768];
    __hip_bfloat16* xs = (__hip_bfloat16*)smem;            // [64][136] padded
    __hip_bfloat16* wl = (__hip_bfloat16*)(smem + 17408);  // [128][128] XOR-swz
    const int tid   = threadIdx.x;
    const int mt    = blockIdx.x;
    const int which = blockIdx.y;        // 0=q 1=k 2=v
    const int b0 = (mt & 7) * 4;
    const int s0 = (mt >> 3) * 16;

    const __hip_bfloat16* wsec = wbf + which * (128 * 128);
    #pragma unroll
    for (int j = 0; j < 8; ++j) {
        int idx = tid + j * 256;
        int fl = idx >> 4, c = idx & 15;
        int cs = c ^ (fl & 15);
        gl_lds16(wsec + fl * 128 + cs * 8, wl + idx * 8);
    }
    #pragma unroll
    for (int j = 0; j < 8; ++j) {
        int idx = tid + j * 256;
        int lt = idx >> 5, c4 = idx & 31;
        int t = (s0 + (lt & 15)) * 32 + b0 + (lt >> 4);
        float4 v = *(const float4*)(x + (size_t)t * 128 + c4 * 4);
        bf16x4 o;
        o[0] = (short)f2bf(v.x); o[1] = (short)f2bf(v.y);
        o[2] = (short)f2bf(v.z); o[3] = (short)f2bf(v.w);
        *(bf16x4*)(xs + lt * 136 + c4 * 4) = o;
    }
    __syncthreads();

    const int wv = tid >> 6, wm = wv >> 1, wn = wv & 1;
    const int l = tid & 63, q15 = l & 15, g = l >> 4;

    bf16x8 xf[2][4];
    #pragma unroll
    for (int tt = 0; tt < 2; ++tt)
        #pragma unroll
        for (int kc = 0; kc < 4; ++kc)
            xf[tt][kc] = *(const bf16x8*)(xs + (wm * 32 + tt * 16 + q15) * 136
                                          + kc * 32 + 8 * g);

    f32x4 acc[4][2];
    #pragma unroll
    for (int nt = 0; nt < 4; ++nt)
        #pragma unroll
        for (int tt = 0; tt < 2; ++tt)
            acc[nt][tt] = (f32x4){0.f, 0.f, 0.f, 0.f};

    #pragma unroll
    for (int nt = 0; nt < 4; ++nt) {
        const int fl = wn * 64 + nt * 16 + q15;
        #pragma unroll
        for (int kc = 0; kc < 4; ++kc) {
            bf16x8 wf = *(const bf16x8*)(wl + fl * 128
                                         + (((kc * 4 + g) ^ q15) * 8));
            acc[nt][0] = __builtin_amdgcn_mfma_f32_16x16x32_bf16(wf, xf[0][kc], acc[nt][0], 0, 0, 0);
            acc[nt][1] = __builtin_amdgcn_mfma_f32_16x16x32_bf16(wf, xf[1][kc], acc[nt][1], 0, 0, 0);
        }
    }
    __syncthreads();
    __hip_bfloat16* ol = wl;

    if (which < 2) {
        #pragma unroll
        for (int nt = 0; nt < 4; ++nt) {
            float4 bv = *(const float4*)(biasf + which * 128 + wn * 64 + nt * 16 + 4 * g);
            #pragma unroll
            for (int tt = 0; tt < 2; ++tt) {
                bf16x4 pk;
                pk[0] = (short)f2bf(acc[nt][tt][0] + bv.x);
                pk[1] = (short)f2bf(acc[nt][tt][1] + bv.y);
                pk[2] = (short)f2bf(acc[nt][tt][2] + bv.z);
                pk[3] = (short)f2bf(acc[nt][tt][3] + bv.w);
                *(bf16x4*)(ol + (wm * 32 + tt * 16 + q15) * 136
                           + wn * 64 + nt * 16 + 4 * g) = pk;
            }
        }
        __syncthreads();
        const int bb = tid >> 6, rr = tid & 63, ss = rr >> 2, c4 = rr & 3;
        __hip_bfloat16* dst = (which == 0) ? qb : kb;
        #pragma unroll
        for (int i = 0; i < 4; ++i) {
            bf16x8 vv = *(const bf16x8*)(ol + (bb * 16 + ss) * 136 + i * 32 + c4 * 8);
            *(bf16x8*)(dst + ((size_t)((b0 + bb) * 4 + i)) * 32768
                       + (s0 + ss) * 32 + c4 * 8) = vv;
        }
    } else {
        #pragma unroll
        for (int nt = 0; nt < 4; ++nt) {
            float4 bv = *(const float4*)(biasf + 256 + wn * 64 + nt * 16 + 4 * g);
            const float* bvp = (const float*)&bv;
            #pragma unroll
            for (int tt = 0; tt < 2; ++tt) {
                #pragma unroll
                for (int r = 0; r < 4; ++r) {
                    int f = wn * 64 + nt * 16 + 4 * g + r;
                    ol[f * 72 + wm * 32 + tt * 16 + q15] =
                        __float2bfloat16(acc[nt][tt][r] + bvp[r]);
                }
            }
        }
        __syncthreads();
        const int bb = tid >> 6, rr = tid & 63, fln = rr >> 1, sh = rr & 1;
        #pragma unroll
        for (int i = 0; i < 4; ++i) {
            int f = i * 32 + fln;
            bf16x8 vv = *(const bf16x8*)(ol + f * 72 + bb * 16 + sh * 8);
            *(bf16x8*)(vtb + ((size_t)((b0 + bb) * 4 + i)) * 32768
                       + (size_t)fln * 1024 + s0 + sh * 8) = vv;
        }
    }
}

// ---------------- Kernel 2: flash attention, counted-vmcnt pipeline ---------
// grid (BH=128, 8), block 256 (4 waves x 32 queries). K/V TRIPLE-buffered in
// LDS: stage tile t+2 while computing t; raw s_barrier with counted
// s_waitcnt vmcnt(2) -- no full vmcnt(0) drain in the steady loop.
// Register-P PV (sigma_g key order), shared K/V fragments across the 2 query
// sub-tiles, no softmax max, ones-B-operand MFMA row sums.
__global__ __launch_bounds__(256)
void attn_kernel(const __hip_bfloat16* __restrict__ qg,
                 const __hip_bfloat16* __restrict__ kg,
                 const __hip_bfloat16* __restrict__ vtg,
                 __hip_bfloat16* __restrict__ att)
{
    __shared__ __hip_bfloat16 Kl[3][64 * 32];
    __shared__ __hip_bfloat16 Vl[3][32 * 64];

    const int tid = threadIdx.x;
    const int w   = tid >> 6;
    const int l   = tid & 63;
    const int q15 = l & 15;
    const int g   = l >> 4;
    const int bh  = blockIdx.x;
    const int qt  = blockIdx.y;          // 0..7, 128 queries per block

    const __hip_bfloat16* kp  = kg  + (size_t)bh * (S_LEN * HDIM);
    const __hip_bfloat16* vtp = vtg + (size_t)bh * (HDIM * S_LEN);

    const int qrow = qt * 128 + w * 32 + q15;
    const __hip_bfloat16* qbase = qg + (size_t)bh * (S_LEN * HDIM);
    bf16x8 qf0 = *(const bf16x8*)(qbase + (size_t)qrow * HDIM + 8 * g);
    bf16x8 qf1 = *(const bf16x8*)(qbase + (size_t)(qrow + 16) * HDIM + 8 * g);

    f32x4 acc00 = {0.f,0.f,0.f,0.f}, acc01 = {0.f,0.f,0.f,0.f}, accs0 = {0.f,0.f,0.f,0.f};
    f32x4 acc10 = {0.f,0.f,0.f,0.f}, acc11 = {0.f,0.f,0.f,0.f}, accs1 = {0.f,0.f,0.f,0.f};

    const short ONE = (short)0x3F80;
    const bf16x8 onef = {ONE, ONE, ONE, ONE, ONE, ONE, ONE, ONE};

    const int kkey = tid >> 2, kd0 = (tid & 3) * 8;
    // V staging: LDS 16B-granule c of row vd holds global granule c^(vd&7)
    const int vd = tid >> 3;
    const int vg0 = ((tid & 7) ^ (vd & 7)) * 8;

    // V read addressing (per lane): rows d0=q15, d1=16+q15 (same &7), byte
    // offset within 16B granule = (g&1)*8; global granule Ga=kc*4+(g>>1),
    // Gb=Ga+2; LDS granule = G ^ (row&7).
    const int vxor = q15 & 7;
    const int vbo  = (g & 1) * 8;
    const int gh   = g >> 1;

#define STAGE(buf, kt_)                                                     \
    gl_lds16(kp + (size_t)((kt_) * 64 + kkey) * HDIM + kd0,                 \
             (void*)(&Kl[buf][0] + tid * 8));                               \
    gl_lds16(vtp + (size_t)vd * S_LEN + (kt_) * 64 + vg0,                   \
             (void*)(&Vl[buf][0] + tid * 8));

#define COMPUTE(buf)                                                        \
    {                                                                       \
        f32x4 sc0[4], sc1[4];                                               \
        _Pragma("unroll")                                                   \
        for (int sub = 0; sub < 4; ++sub) {                                 \
            bf16x8 kf = *(const bf16x8*)(&Kl[buf][(sub * 16 + q15) * HDIM + 8 * g]); \
            f32x4 z = {0.f, 0.f, 0.f, 0.f};                                 \
            sc0[sub] = __builtin_amdgcn_mfma_f32_16x16x32_bf16(kf, qf0, z, 0, 0, 0); \
            sc1[sub] = __builtin_amdgcn_mfma_f32_16x16x32_bf16(kf, qf1, z, 0, 0, 0); \
        }                                                                   \
        const char* vbase = (const char*)&Vl[buf][0];                       \
        bf16x8 vf00, vf01, vf10, vf11;                                      \
        {                                                                   \
            const int Ga0 = gh,     Gb0 = gh + 2;                           \
            const int Ga1 = 4 + gh, Gb1 = 6 + gh;                           \
            bf16x4 a0 = *(const bf16x4*)(vbase + q15 * 128 + ((Ga0 ^ vxor) * 16) + vbo); \
            bf16x4 a1 = *(const bf16x4*)(vbase + q15 * 128 + ((Gb0 ^ vxor) * 16) + vbo); \
            bf16x4 b0 = *(const bf16x4*)(vbase + (16 + q15) * 128 + ((Ga0 ^ vxor) * 16) + vbo); \
            bf16x4 b1 = *(const bf16x4*)(vbase + (16 + q15) * 128 + ((Gb0 ^ vxor) * 16) + vbo); \
            bf16x4 c0 = *(const bf16x4*)(vbase + q15 * 128 + ((Ga1 ^ vxor) * 16) + vbo); \
            bf16x4 c1 = *(const bf16x4*)(vbase + q15 * 128 + ((Gb1 ^ vxor) * 16) + vbo); \
            bf16x4 d0 = *(const bf16x4*)(vbase + (16 + q15) * 128 + ((Ga1 ^ vxor) * 16) + vbo); \
            bf16x4 d1 = *(const bf16x4*)(vbase + (16 + q15) * 128 + ((Gb1 ^ vxor) * 16) + vbo); \
            vf00 = __builtin_shufflevector(a0, a1, 0, 1, 2, 3, 4, 5, 6, 7); \
            vf01 = __builtin_shufflevector(b0, b1, 0, 1, 2, 3, 4, 5, 6, 7); \
            vf10 = __builtin_shufflevector(c0, c1, 0, 1, 2, 3, 4, 5, 6, 7); \
            vf11 = __builtin_shufflevector(d0, d1, 0, 1, 2, 3, 4, 5, 6, 7); \
        }                                                                   \
        bf16x8 pf00, pf01, pf10, pf11;                                      \
        {                                                                   \
            u32x4 t;                                                        \
            float e0, e1, e2, e3, e4, e5, e6, e7;                           \
            PACKP(pf00, sc0[0], sc0[1])                                     \
            PACKP(pf01, sc0[2], sc0[3])                                     \
            PACKP(pf10, sc1[0], sc1[1])                                     \
            PACKP(pf11, sc1[2], sc1[3])                                     \
        }                                                                   \
        acc00 = __builtin_amdgcn_mfma_f32_16x16x32_bf16(pf00, vf00, acc00, 0, 0, 0); \
        acc01 = __builtin_amdgcn_mfma_f32_16x16x32_bf16(pf00, vf01, acc01, 0, 0, 0); \
        accs0 = __builtin_amdgcn_mfma_f32_16x16x32_bf16(pf00, onef, accs0, 0, 0, 0); \
        acc10 = __builtin_amdgcn_mfma_f32_16x16x32_bf16(pf10, vf00, acc10, 0, 0, 0); \
        acc11 = __builtin_amdgcn_mfma_f32_16x16x32_bf16(pf10, vf01, acc11, 0, 0, 0); \
        accs1 = __builtin_amdgcn_mfma_f32_16x16x32_bf16(pf10, onef, accs1, 0, 0, 0); \
        acc00 = __builtin_amdgcn_mfma_f32_16x16x32_bf16(pf01, vf10, acc00, 0, 0, 0); \
        acc01 = __builtin_amdgcn_mfma_f32_16x16x32_bf16(pf01, vf11, acc01, 0, 0, 0); \
        accs0 = __builtin_amdgcn_mfma_f32_16x16x32_bf16(pf01, onef, accs0, 0, 0, 0); \
        acc10 = __builtin_amdgcn_mfma_f32_16x16x32_bf16(pf11, vf10, acc10, 0, 0, 0); \
        acc11 = __builtin_amdgcn_mfma_f32_16x16x32_bf16(pf11, vf11, acc11, 0, 0, 0); \
        accs1 = __builtin_amdgcn_mfma_f32_16x16x32_bf16(pf11, onef, accs1, 0, 0, 0); \
    }

#define PACKP(dst, SA, SB)                                                \
    e0 = __builtin_amdgcn_exp2f(SA[0]);                                   \
    e1 = __builtin_amdgcn_exp2f(SA[1]);                                   \
    e2 = __builtin_amdgcn_exp2f(SA[2]);                                   \
    e3 = __builtin_amdgcn_exp2f(SA[3]);                                   \
    e4 = __builtin_amdgcn_exp2f(SB[0]);                                   \
    e5 = __builtin_amdgcn_exp2f(SB[1]);                                   \
    e6 = __builtin_amdgcn_exp2f(SB[2]);                                   \
    e7 = __builtin_amdgcn_exp2f(SB[3]);                                   \
    t[0] = __builtin_amdgcn_perm(__float_as_uint(e1),                     \
                                 __float_as_uint(e0), 0x07060302u);       \
    t[1] = __builtin_amdgcn_perm(__float_as_uint(e3),                     \
                                 __float_as_uint(e2), 0x07060302u);       \
    t[2] = __builtin_amdgcn_perm(__float_as_uint(e5),                     \
                                 __float_as_uint(e4), 0x07060302u);       \
    t[3] = __builtin_amdgcn_perm(__float_as_uint(e7),                     \
                                 __float_as_uint(e6), 0x07060302u);       \
    __builtin_memcpy(&dst, &t, 16);

    // ---- prologue: stage tiles 0 and 1; wait only for tile 0
    STAGE(0, 0)
    STAGE(1, 1)
    asm volatile("s_waitcnt vmcnt(2)" ::: "memory");
    __builtin_amdgcn_s_barrier();
    asm volatile("" ::: "memory");

    // ---- steady state: stage t+2, compute t, counted-vmcnt barrier
    #pragma unroll
    for (int kt = 0; kt < 14; ++kt) {
        const int cb = kt % 3;
        const int sb = (kt + 2) % 3;
        STAGE(sb, kt + 2)
        COMPUTE(cb)
        asm volatile("s_waitcnt vmcnt(2)" ::: "memory");
        __builtin_amdgcn_s_barrier();
        asm volatile("" ::: "memory");
        __builtin_amdgcn_sched_barrier(0);
    }
    // ---- kt = 14: nothing left to stage; drain for tile 15
    COMPUTE(2)
    asm volatile("s_waitcnt vmcnt(0)" ::: "memory");
    __builtin_amdgcn_s_barrier();
    asm volatile("" ::: "memory");
    // ---- kt = 15
    COMPUTE(0)

#undef STAGE
#undef COMPUTE
#undef PACKP

    // ---- epilogue: normalize by ones row sums (lane-local), write bf16
    const int b = bh >> 2, h = bh & 3;
    #pragma unroll
    for (int r = 0; r < 4; ++r) {
        const float i0 = 1.f / accs0[r];
        const float i1 = 1.f / accs1[r];
        const int s0r = qt * 128 + w * 32 + 4 * g + r;
        __hip_bfloat16* ap0 = att + ((size_t)s0r * BATCH + b) * EMB + h * HDIM;
        __hip_bfloat16* ap1 = att + ((size_t)(s0r + 16) * BATCH + b) * EMB + h * HDIM;
        ap0[q15]      = __float2bfloat16(acc00[r] * i0);
        ap0[16 + q15] = __float2bfloat16(acc01[r] * i0);
        ap1[q15]      = __float2bfloat16(acc10[r] * i1);
        ap1[16 + q15] = __float2bfloat16(acc11[r] * i1);
    }
}

// ---------------- Kernel 3: out_proj MFMA + bias + residual + LayerNorm ----
// grid 512: 64 tokens x 128 f per block. 4 waves 2x2; Wo and att staged.
__global__ __launch_bounds__(256)
void proj_ln_mfma(const float* __restrict__ x,
                  const __hip_bfloat16* __restrict__ att,
                  const __hip_bfloat16* __restrict__ wobf,
                  const float* __restrict__ biasf,
                  const float* __restrict__ gm, const float* __restrict__ bt,
                  float* __restrict__ out)
{
    __shared__ __align__(16) unsigned char smem[32768 + 16384 + 1024];
    __hip_bfloat16* wl = (__hip_bfloat16*)smem;              // [128][128] XOR-swz
    __hip_bfloat16* al = (__hip_bfloat16*)(smem + 32768);    // [64][128] XOR-swz
    float* red = (float*)(smem + 32768 + 16384);             // [2][128]

    const int tid = threadIdx.x;
    const int t0  = blockIdx.x * 64;

    #pragma unroll
    for (int j = 0; j < 8; ++j) {
        int idx = tid + j * 256;
        int fl = idx >> 4, c = idx & 15;
        int cs = c ^ (fl & 15);
        gl_lds16(wobf + fl * 128 + cs * 8, wl + idx * 8);
    }
    #pragma unroll
    for (int j = 0; j < 4; ++j) {
        int idx = tid + j * 256;
        int fl = idx >> 4, c = idx & 15;
        int cs = c ^ (fl & 15);
        gl_lds16(att + (size_t)(t0 + fl) * 128 + cs * 8, al + idx * 8);
    }
    __syncthreads();

    const int wv = tid >> 6, wm = wv >> 1, wn = wv & 1;
    const int l = tid & 63, q15 = l & 15, g = l >> 4;

    bf16x8 af[2][4];
    #pragma unroll
    for (int tt = 0; tt < 2; ++tt)
        #pragma unroll
        for (int kc = 0; kc < 4; ++kc)
            af[tt][kc] = *(const bf16x8*)(al + (wm * 32 + tt * 16 + q15) * 128
                                          + (((kc * 4 + g) ^ q15) * 8));

    f32x4 acc[4][2];
    #pragma unroll
    for (int nt = 0; nt < 4; ++nt)
        #pragma unroll
        for (int tt = 0; tt < 2; ++tt)
            acc[nt][tt] = (f32x4){0.f, 0.f, 0.f, 0.f};

    #pragma unroll
    for (int nt = 0; nt < 4; ++nt) {
        const int fl = wn * 64 + nt * 16 + q15;
        #pragma unroll
        for (int kc = 0; kc < 4; ++kc) {
            bf16x8 wf = *(const bf16x8*)(wl + fl * 128
                                         + (((kc * 4 + g) ^ q15) * 8));
            acc[nt][0] = __builtin_amdgcn_mfma_f32_16x16x32_bf16(wf, af[0][kc], acc[nt][0], 0, 0, 0);
            acc[nt][1] = __builtin_amdgcn_mfma_f32_16x16x32_bf16(wf, af[1][kc], acc[nt][1], 0, 0, 0);
        }
    }

    float vv[4][2][4];
    float psum[2] = {0.f, 0.f}, psq[2] = {0.f, 0.f};
    #pragma unroll
    for (int nt = 0; nt < 4; ++nt) {
        const int f0 = wn * 64 + nt * 16 + 4 * g;
        float4 bv = *(const float4*)(biasf + 384 + f0);
        const float* bvp = (const float*)&bv;
        #pragma unroll
        for (int tt = 0; tt < 2; ++tt) {
            const int t = t0 + wm * 32 + tt * 16 + q15;
            float4 xv = *(const float4*)(x + (size_t)t * 128 + f0);
            const float* xvp = (const float*)&xv;
            #pragma unroll
            for (int r = 0; r < 4; ++r) {
                float v = acc[nt][tt][r] + bvp[r] + xvp[r];
                vv[nt][tt][r] = v;
                psum[tt] += v;
                psq[tt]  = fmaf(v, v, psq[tt]);
            }
        }
    }
    #pragma unroll
    for (int tt = 0; tt < 2; ++tt) {
        psum[tt] += __shfl_xor(psum[tt], 16);
        psum[tt] += __shfl_xor(psum[tt], 32);
        psq[tt]  += __shfl_xor(psq[tt], 16);
        psq[tt]  += __shfl_xor(psq[tt], 32);
    }
    if (l < 16) {
        #pragma unroll
        for (int tt = 0; tt < 2; ++tt) {
            int idx = ((wn * 2 + wm) * 2 + tt) * 16 + q15;
            red[idx]       = psum[tt];
            red[128 + idx] = psq[tt];
        }
    }
    __syncthreads();

    float mean[2], rstd[2];
    #pragma unroll
    for (int tt = 0; tt < 2; ++tt) {
        int oidx = (((wn ^ 1) * 2 + wm) * 2 + tt) * 16 + q15;
        float s  = psum[tt] + red[oidx];
        float sq = psq[tt]  + red[128 + oidx];
        mean[tt] = s * (1.f / 128.f);
        float var = sq * (1.f / 128.f) - mean[tt] * mean[tt];
        rstd[tt] = rsqrtf(var + 1e-5f);
    }

    #pragma unroll
    for (int nt = 0; nt < 4; ++nt) {
        const int f0 = wn * 64 + nt * 16 + 4 * g;
        float4 gv  = *(const float4*)(gm + f0);
        float4 btv = *(const float4*)(bt + f0);
        const float* gvp = (const float*)&gv;
        const float* btp = (const float*)&btv;
        #pragma unroll
        for (int tt = 0; tt < 2; ++tt) {
            const int t = t0 + wm * 32 + tt * 16 + q15;
            float4 o;
            float* op = (float*)&o;
            #pragma unroll
            for (int r = 0; r < 4; ++r)
                op[r] = (vv[nt][tt][r] - mean[tt]) * rstd[tt] * gvp[r] + btp[r];
            *(float4*)(out + (size_t)t * 128 + f0) = o;
        }
    }
}

extern "C" void kernel_launch(void* const* d_in, const int* in_sizes, int n_in,
                              void* d_out, int out_size, void* d_ws, size_t ws_size,
                              hipStream_t stream) {
    const float* x     = (const float*)d_in[0];
    const float* wi    = (const float*)d_in[1];
    const float* bi    = (const float*)d_in[2];
    const float* wo    = (const float*)d_in[3];
    const float* bo    = (const float*)d_in[4];
    const float* gamma = (const float*)d_in[5];
    const float* beta  = (const float*)d_in[6];
    float* out = (float*)d_out;

    unsigned char* wsb = (unsigned char*)d_ws;
    __hip_bfloat16* wbf   = (__hip_bfloat16*)wsb;               // 98304 B
    __hip_bfloat16* wobf  = (__hip_bfloat16*)(wsb + 98304);     // 32768 B
    float*          biasf = (float*)(wsb + 131072);             // 2048 B
    __hip_bfloat16* qb    = (__hip_bfloat16*)(wsb + 133120);    // 8 MB each
    __hip_bfloat16* kb    = qb + HBUF;
    __hip_bfloat16* vtb   = kb + HBUF;
    __hip_bfloat16* att   = vtb + HBUF;                          // 8 MB

    wcvt_kernel<<<65, 256, 0, stream>>>(wi, bi, wo, bo, wbf, wobf, biasf);
    qkv_mfma_kernel<<<dim3(512, 3), 256, 0, stream>>>(x, wbf, biasf, qb, kb, vtb);
    attn_kernel<<<dim3(BHN, 8), 256, 0, stream>>>(qb, kb, vtb, att);
    proj_ln_mfma<<<512, 256, 0, stream>>>(x, att, wobf, biasf, gamma, beta, out);
}